// Round 6
// baseline (181.817 us; speedup 1.0000x reference)
//
#include <hip/hip_runtime.h>

#define LSEQ 8192
#define NBAT 16
#define DMOD 16
#define DINN 32
#define DSTA 16
#define CL   64
#define NCH  (LSEQ / CL)            // 128
#define NCHT (NBAT * NCH)           // 2048
#define CHF  (96 * CL)              // 6144 floats per chunk record (comp-major)
#define NROWS (NBAT * LSEQ)         // 131072
#define SUMN ((size_t)NCHT * 512)

typedef __attribute__((ext_vector_type(8))) short bf16x8;
typedef __attribute__((ext_vector_type(4))) float f32x4;

__device__ __forceinline__ float fsilu(float v) { return v / (1.f + __expf(-v)); }
__device__ __forceinline__ float fsoftplus(float v) {
  return v > 20.f ? v : __logf(1.f + __expf(v));
}
__device__ __forceinline__ short f2bf(float f) {
  union { float f; unsigned u; } v; v.f = f;
  unsigned r = (v.u + 0x7fffu + ((v.u >> 16) & 1u)) >> 16;
  return (short)r;
}

__device__ __forceinline__ void load_x_row(const float* __restrict__ x, long r,
                                           float* __restrict__ xr) {
  const float4* xp = reinterpret_cast<const float4*>(x + r * DMOD);
  float4 v0 = xp[0], v1 = xp[1], v2 = xp[2], v3 = xp[3];
  xr[0] = v0.x; xr[1] = v0.y; xr[2] = v0.z; xr[3] = v0.w;
  xr[4] = v1.x; xr[5] = v1.y; xr[6] = v1.z; xr[7] = v1.w;
  xr[8] = v2.x; xr[9] = v2.y; xr[10] = v2.z; xr[11] = v2.w;
  xr[12] = v3.x; xr[13] = v3.y; xr[14] = v3.z; xr[15] = v3.w;
}

// 16 columns [hf*16, hf*16+16) of xm = rmsnorm(x_row) @ ipw[:, 0:32]
__device__ __forceinline__ void xm_half(const float* __restrict__ x,
                                        const float* __restrict__ rms1w,
                                        const float* __restrict__ ipw, long r,
                                        int hf, float* __restrict__ o) {
  float xr[16];
  load_x_row(x, r, xr);
  float ss = 0.f;
#pragma unroll
  for (int i = 0; i < 16; i++) ss += xr[i] * xr[i];
  float inv = rsqrtf(ss * (1.f / 16.f) + 1e-6f);
#pragma unroll
  for (int k = 0; k < 16; k++) o[k] = 0.f;
#pragma unroll
  for (int i = 0; i < 16; i++) {
    float xi = xr[i] * inv * rms1w[i];
#pragma unroll
    for (int k = 0; k < 16; k++)
      o[k] = fmaf(xi, ipw[i * 64 + hf * 16 + k], o[k]);
  }
}

// ---- K1: fused prep + per-chunk local scan.  128 thr / 1 chunk.
// rec[chunk][c][64], c: dt[0:32) xc[32:64) B[64:80) C[80:96)
__global__ __launch_bounds__(128) void k_prep2(
    const float* __restrict__ x, const float* __restrict__ rms1w,
    const float* __restrict__ ipw, const float* __restrict__ cw,
    const float* __restrict__ cb, const float* __restrict__ xpw,
    const float* __restrict__ dtw, const float* __restrict__ dtb,
    const float* __restrict__ A_log, float* __restrict__ rec,
    float* __restrict__ Pb, float* __restrict__ Hb) {
  __shared__ float xmv[67][33];  // xm rows (3 halo + 64); later proj[64][33]
  __shared__ float xcf[64][33];  // xc f32
  __shared__ float dts[64][33];  // dt f32
  int t = threadIdx.x, bc = blockIdx.x;
  long row0 = (long)bc * CL;
  int l0 = (int)(row0 & (LSEQ - 1));
  int l = t >> 1, hf = t & 1, d0 = hf * 16;

  // Phase A: xm halves (thread pair per row); halo rows on threads 0..5
  {
    float o[16];
    xm_half(x, rms1w, ipw, row0 + l, hf, o);
#pragma unroll
    for (int k = 0; k < 16; k++) xmv[3 + l][d0 + k] = o[k];
  }
  if (t < 6) {
    int hi = t >> 1;
    if (l0 == 0) {
#pragma unroll
      for (int k = 0; k < 16; k++) xmv[hi][d0 + k] = 0.f;
    } else {
      float o[16];
      xm_half(x, rms1w, ipw, row0 - 3 + hi, hf, o);
#pragma unroll
      for (int k = 0; k < 16; k++) xmv[hi][d0 + k] = o[k];
    }
  }
  __syncthreads();

  // Phase B: causal conv + silu for 16 d's
#pragma unroll
  for (int dd = 0; dd < 16; dd++) {
    int d = d0 + dd;
    float c = cb[d];
#pragma unroll
    for (int k = 0; k < 4; k++) c = fmaf(cw[d * 4 + k], xmv[l + k][d], c);
    xcf[l][d] = fsilu(c);
  }
  __syncthreads();

  // Phase C: proj cols (hf0: 0..16 = dt_in+B, hf1: 17..32 = C) into xmv[l][*]
  {
    float xcr[32];
#pragma unroll
    for (int d = 0; d < 32; d++) xcr[d] = xcf[l][d];
    int j0 = hf ? 17 : 0;
    int jmax = hf ? 32 : 16;
#pragma unroll
    for (int jj = 0; jj < 17; jj++) {
      int j = j0 + jj;
      if (j <= jmax) {
        float acc = 0.f;
#pragma unroll
        for (int d = 0; d < 32; d++) acc = fmaf(xcr[d], xpw[d * 33 + j], acc);
        xmv[l][j] = acc;
      }
    }
  }
  __syncthreads();

  // Phase D: dt = softplus(p0*dtw + dtb) for 16 d's
  {
    float p0 = xmv[l][0];
#pragma unroll
    for (int dd = 0; dd < 16; dd++) {
      int d = d0 + dd;
      dts[l][d] = fsoftplus(p0 * dtw[d] + dtb[d]);
    }
  }
  __syncthreads();

  // Phase E: coalesced comp-major global writes
  {
    float* base = rec + (size_t)bc * CHF;
#pragma unroll
    for (int i = 0; i < 48; i++) {
      int idx = i * 128 + t;
      int c = idx >> 6, l2 = idx & 63;
      float v;
      if (c < 32) v = dts[l2][c];
      else if (c < 64) v = xcf[l2][c - 32];
      else if (c < 80) v = xmv[l2][1 + (c - 64)];
      else v = xmv[l2][17 + (c - 80)];
      base[idx] = v;
    }
  }

  // Phase F: per-chunk local scan -> P (decay), H (state from h0=0)
  {
    int d = t >> 2, s4 = (t & 3) << 2;
    float4 al = *reinterpret_cast<const float4*>(A_log + d * DSTA + s4);
    float Ad[4] = {-__expf(al.x), -__expf(al.y), -__expf(al.z), -__expf(al.w)};
    float H[4] = {0.f, 0.f, 0.f, 0.f};
    float sumdt = 0.f;
#pragma unroll 4
    for (int li = 0; li < CL; li++) {
      float dt = dts[li][d];
      float xcv = xcf[li][d];
      float dx = dt * xcv;
      sumdt += dt;
      float a;
      a = __expf(dt * Ad[0]); H[0] = fmaf(a, H[0], dx * xmv[li][1 + s4]);
      a = __expf(dt * Ad[1]); H[1] = fmaf(a, H[1], dx * xmv[li][2 + s4]);
      a = __expf(dt * Ad[2]); H[2] = fmaf(a, H[2], dx * xmv[li][3 + s4]);
      a = __expf(dt * Ad[3]); H[3] = fmaf(a, H[3], dx * xmv[li][4 + s4]);
    }
    size_t base = (size_t)bc * 512 + (size_t)(d * 16 + s4);
    *reinterpret_cast<float4*>(Pb + base) =
        make_float4(__expf(sumdt * Ad[0]), __expf(sumdt * Ad[1]),
                    __expf(sumdt * Ad[2]), __expf(sumdt * Ad[3]));
    *reinterpret_cast<float4*>(Hb + base) = make_float4(H[0], H[1], H[2], H[3]);
  }
}

// ---- K2: exclusive scan over chunks
__global__ __launch_bounds__(64) void k_combine(const float* __restrict__ Pb,
                                                const float* __restrict__ Hb,
                                                float* __restrict__ hs) {
  int g = blockIdx.x * 64 + threadIdx.x;
  int b = g >> 9, st = g & 511;
  size_t base = (size_t)b * NCH * 512 + st;
  float h = 0.f;
#pragma unroll 8
  for (int c = 0; c < NCH; c++) {
    size_t o = base + (size_t)c * 512;
    hs[o] = h;
    h = fmaf(Pb[o], h, Hb[o]);
  }
}

// ---- K3: fused per-chunk scan + MFMA epilogue
__device__ __forceinline__ f32x4 mm(bf16x8 a, bf16x8 b, f32x4 c) {
  return __builtin_amdgcn_mfma_f32_16x16x32_bf16(a, b, c, 0, 0, 0);
}
__device__ __forceinline__ bf16x8 bfrag(const float* __restrict__ W, int ldw,
                                        int coloff, int col, int kg, int kreal) {
  bf16x8 b = {0, 0, 0, 0, 0, 0, 0, 0};
#pragma unroll
  for (int e = 0; e < 8; e++) {
    int k = kg * 8 + e;
    if (k < kreal) b[e] = f2bf(W[k * ldw + coloff + col]);
  }
  return b;
}
__device__ __forceinline__ bf16x8 afrag(const float* sb, int lrow, int kg,
                                        int kreal) {
  bf16x8 a = {0, 0, 0, 0, 0, 0, 0, 0};
  if (kg * 8 < kreal) {
    const float4* p = reinterpret_cast<const float4*>(sb + lrow * 36 + kg * 8);
    float4 u = p[0], v = p[1];
    a[0] = f2bf(u.x); a[1] = f2bf(u.y); a[2] = f2bf(u.z); a[3] = f2bf(u.w);
    a[4] = f2bf(v.x); a[5] = f2bf(v.y); a[6] = f2bf(v.z); a[7] = f2bf(v.w);
  }
  return a;
}

__global__ __launch_bounds__(128) void k_scanmlp(
    const float* __restrict__ rec, const float* __restrict__ x,
    const float* __restrict__ A_log, const float* __restrict__ hs,
    const float* __restrict__ rms1w, const float* __restrict__ ipw,
    const float* __restrict__ Dskip, const float* __restrict__ opw,
    const float* __restrict__ rms2w, const float* __restrict__ f1w,
    const float* __restrict__ f1b, const float* __restrict__ f2w,
    const float* __restrict__ f2b, const float* __restrict__ f3w,
    const float* __restrict__ f3b, float* __restrict__ out) {
  __shared__ float sm[96 * 65];
  __shared__ float sb[64 * 36];
  __shared__ short x0b[64][24];
  int t = threadIdx.x, bc = blockIdx.x;
  const float* cbase = rec + (size_t)bc * CHF;
#pragma unroll
  for (int i = 0; i < 12; i++) {
    int g4 = i * 512 + t * 4;
    int c = g4 >> 6, l = g4 & 63;
    *reinterpret_cast<float4*>(&sm[c * 65 + l]) =
        *reinterpret_cast<const float4*>(cbase + g4);
  }
  if (t < 64) {
    float xr[16];
    load_x_row(x, (long)bc * CL + t, xr);
    float ss = 0.f;
#pragma unroll
    for (int i = 0; i < 16; i++) ss += xr[i] * xr[i];
    float inv1 = rsqrtf(ss * (1.f / 16.f) + 1e-6f);
#pragma unroll
    for (int i = 0; i < 4; i++) {
      float a0 = xr[i * 4 + 0] * inv1 * rms1w[i * 4 + 0];
      float a1 = xr[i * 4 + 1] * inv1 * rms1w[i * 4 + 1];
      float a2 = xr[i * 4 + 2] * inv1 * rms1w[i * 4 + 2];
      float a3 = xr[i * 4 + 3] * inv1 * rms1w[i * 4 + 3];
      unsigned u0 = ((unsigned)(unsigned short)f2bf(a0)) |
                    (((unsigned)(unsigned short)f2bf(a1)) << 16);
      unsigned u1 = ((unsigned)(unsigned short)f2bf(a2)) |
                    (((unsigned)(unsigned short)f2bf(a3)) << 16);
      *reinterpret_cast<uint2*>(&x0b[t][i * 4]) = make_uint2(u0, u1);
    }
  }
  __syncthreads();

  // scan; y overwrites the dead dt slot (wave-partitioned by d)
  {
    int d = t >> 2, s4 = (t & 3) << 2;
    float4 al = *reinterpret_cast<const float4*>(A_log + d * DSTA + s4);
    float Ad[4] = {-__expf(al.x), -__expf(al.y), -__expf(al.z), -__expf(al.w)};
    float h[4];
    float4 hv = *reinterpret_cast<const float4*>(hs + (size_t)bc * 512 +
                                                 (size_t)(d * 16 + s4));
    h[0] = hv.x; h[1] = hv.y; h[2] = hv.z; h[3] = hv.w;
    int dof = d * 65, xof = (32 + d) * 65;
    int bof0 = (64 + s4) * 65, bof1 = (65 + s4) * 65, bof2 = (66 + s4) * 65,
        bof3 = (67 + s4) * 65;
    int cof0 = (80 + s4) * 65, cof1 = (81 + s4) * 65, cof2 = (82 + s4) * 65,
        cof3 = (83 + s4) * 65;
    bool wy = (t & 3) == 0;
#pragma unroll 2
    for (int l = 0; l < CL; l++) {
      float dt = sm[dof + l];
      float xcv = sm[xof + l];
      float dx = dt * xcv;
      float a;
      a = __expf(dt * Ad[0]); h[0] = fmaf(a, h[0], dx * sm[bof0 + l]);
      a = __expf(dt * Ad[1]); h[1] = fmaf(a, h[1], dx * sm[bof1 + l]);
      a = __expf(dt * Ad[2]); h[2] = fmaf(a, h[2], dx * sm[bof2 + l]);
      a = __expf(dt * Ad[3]); h[3] = fmaf(a, h[3], dx * sm[bof3 + l]);
      float y = sm[cof0 + l] * h[0];
      y = fmaf(sm[cof1 + l], h[1], y);
      y = fmaf(sm[cof2 + l], h[2], y);
      y = fmaf(sm[cof3 + l], h[3], y);
      y += __shfl_xor(y, 1);
      y += __shfl_xor(y, 2);
      if (wy) sm[dof + l] = y;
    }
  }
  __syncthreads();

  // MFMA epilogue: 2 waves x 32 rows
  {
    int lane = t & 63, w = t >> 6;
    int col = lane & 15, kg = lane >> 4;
    bf16x8 Bz0 = bfrag(ipw + 32, 64, 0, col, kg, 16);
    bf16x8 Bz1 = bfrag(ipw + 32, 64, 16, col, kg, 16);
    bf16x8 Bop = bfrag(opw, 16, 0, col, kg, 32);
    bf16x8 Bf1_0 = bfrag(f1w, 32, 0, col, kg, 16);
    bf16x8 Bf1_1 = bfrag(f1w, 32, 16, col, kg, 16);
    bf16x8 Bf2_0 = bfrag(f2w, 32, 0, col, kg, 32);
    bf16x8 Bf2_1 = bfrag(f2w, 32, 16, col, kg, 32);
    bf16x8 Bf3 = bfrag(f3w, 16, 0, col, kg, 32);
    float b1_0 = f1b[col], b1_1 = f1b[16 + col];
    float b2_0 = f2b[col], b2_1 = f2b[16 + col];
    float b3_c = f3b[col];
    float dsk0 = Dskip[col], dsk1 = Dskip[16 + col];
    float rw2 = rms2w[col];
    const f32x4 zero4 = {0.f, 0.f, 0.f, 0.f};
    long rowbase = (long)bc * CL;
#pragma unroll 1
    for (int rt = 0; rt < 2; rt++) {
      int tile0 = w * 32 + rt * 16;
      bf16x8 ax0 = {0, 0, 0, 0, 0, 0, 0, 0};
      if (kg < 2)
        ax0 = *reinterpret_cast<const bf16x8*>(&x0b[tile0 + col][kg * 8]);
      f32x4 zf0 = mm(ax0, Bz0, zero4);
      f32x4 zf1 = mm(ax0, Bz1, zero4);
#pragma unroll
      for (int reg = 0; reg < 4; reg++) {
        int lrow = tile0 + kg * 4 + reg;
        float y0 = sm[col * 65 + lrow];
        float y1 = sm[(16 + col) * 65 + lrow];
        float xc0 = sm[(32 + col) * 65 + lrow];
        float xc1 = sm[(48 + col) * 65 + lrow];
        sb[lrow * 36 + col] = (y0 + dsk0 * xc0) * fsilu(zf0[reg]);
        sb[lrow * 36 + 16 + col] = (y1 + dsk1 * xc1) * fsilu(zf1[reg]);
      }
      bf16x8 ayo = afrag(sb, tile0 + col, kg, 32);
      f32x4 x1f = mm(ayo, Bop, zero4);
      float xres[4];
#pragma unroll
      for (int reg = 0; reg < 4; reg++) {
        long grow = rowbase + tile0 + kg * 4 + reg;
        xres[reg] = x1f[reg] + x[grow * 16 + col];
      }
#pragma unroll
      for (int reg = 0; reg < 4; reg++) {
        float ss = xres[reg] * xres[reg];
        ss += __shfl_xor(ss, 1);
        ss += __shfl_xor(ss, 2);
        ss += __shfl_xor(ss, 4);
        ss += __shfl_xor(ss, 8);
        float inv2 = rsqrtf(ss * (1.f / 16.f) + 1e-6f);
        sb[(tile0 + kg * 4 + reg) * 36 + col] = xres[reg] * inv2 * rw2;
      }
      bf16x8 ax2 = afrag(sb, tile0 + col, kg, 16);
      f32x4 h1f0 = mm(ax2, Bf1_0, zero4);
      f32x4 h1f1 = mm(ax2, Bf1_1, zero4);
#pragma unroll
      for (int reg = 0; reg < 4; reg++) {
        int lrow = tile0 + kg * 4 + reg;
        sb[lrow * 36 + col] = fmaxf(h1f0[reg] + b1_0, 0.f);
        sb[lrow * 36 + 16 + col] = fmaxf(h1f1[reg] + b1_1, 0.f);
      }
      bf16x8 ah1 = afrag(sb, tile0 + col, kg, 32);
      f32x4 h2f0 = mm(ah1, Bf2_0, zero4);
      f32x4 h2f1 = mm(ah1, Bf2_1, zero4);
#pragma unroll
      for (int reg = 0; reg < 4; reg++) {
        int lrow = tile0 + kg * 4 + reg;
        sb[lrow * 36 + col] = fmaxf(h2f0[reg] + b2_0, 0.f);
        sb[lrow * 36 + 16 + col] = fmaxf(h2f1[reg] + b2_1, 0.f);
      }
      bf16x8 ah2 = afrag(sb, tile0 + col, kg, 32);
      f32x4 x3f = mm(ah2, Bf3, zero4);
#pragma unroll
      for (int reg = 0; reg < 4; reg++) {
        long grow = rowbase + tile0 + kg * 4 + reg;
        out[grow * 16 + col] = xres[reg] + x3f[reg] + b3_c;
      }
    }
  }
}

extern "C" void kernel_launch(void* const* d_in, const int* in_sizes, int n_in,
                              void* d_out, int out_size, void* d_ws,
                              size_t ws_size, hipStream_t stream) {
  const float* x = (const float*)d_in[0];
  const float* rms1w = (const float*)d_in[1];
  const float* ipw = (const float*)d_in[2];
  const float* cw = (const float*)d_in[3];
  const float* cb = (const float*)d_in[4];
  const float* xpw = (const float*)d_in[5];
  const float* dtw = (const float*)d_in[6];
  const float* dtb = (const float*)d_in[7];
  const float* A_log = (const float*)d_in[8];
  const float* Dskip = (const float*)d_in[9];
  const float* opw = (const float*)d_in[10];
  const float* rms2w = (const float*)d_in[11];
  const float* f1w = (const float*)d_in[12];
  const float* f1b = (const float*)d_in[13];
  const float* f2w = (const float*)d_in[14];
  const float* f2b = (const float*)d_in[15];
  const float* f3w = (const float*)d_in[16];
  const float* f3b = (const float*)d_in[17];
  float* out = (float*)d_out;

  float* rec = (float*)d_ws;                  // 50.3 MiB
  float* Pb = rec + (size_t)NCHT * CHF;       // 4 MiB
  float* Hb = Pb + SUMN;                      // 4 MiB
  float* hsb = Hb + SUMN;                     // 4 MiB

  hipLaunchKernelGGL(k_prep2, dim3(NCHT), dim3(128), 0, stream, x, rms1w, ipw,
                     cw, cb, xpw, dtw, dtb, A_log, rec, Pb, Hb);
  hipLaunchKernelGGL(k_combine, dim3((NBAT * 512) / 64), dim3(64), 0, stream,
                     Pb, Hb, hsb);
  hipLaunchKernelGGL(k_scanmlp, dim3(NCHT), dim3(128), 0, stream, rec, x,
                     A_log, hsb, rms1w, ipw, Dskip, opw, rms2w, f1w, f1b, f2w,
                     f2b, f3w, f3b, out);
}

// Round 7
// 118.052 us; speedup vs baseline: 1.5402x; 1.5402x over previous
//
#include <hip/hip_runtime.h>

#define LSEQ 8192
#define NBAT 16
#define DMOD 16
#define DINN 32
#define DSTA 16
#define CL   64
#define NCH  (LSEQ / CL)            // 128
#define NCHT (NBAT * NCH)           // 2048
#define CHF  (96 * CL)              // 6144 floats per chunk record (comp-major)
#define NROWS (NBAT * LSEQ)         // 131072
#define SUMN ((size_t)NCHT * 512)

typedef __attribute__((ext_vector_type(8))) short bf16x8;
typedef __attribute__((ext_vector_type(4))) float f32x4;

__device__ __forceinline__ float fsilu(float v) { return v / (1.f + __expf(-v)); }
__device__ __forceinline__ float fsoftplus(float v) {
  return v > 20.f ? v : __logf(1.f + __expf(v));
}
__device__ __forceinline__ short f2bf(float f) {
  union { float f; unsigned u; } v; v.f = f;
  unsigned r = (v.u + 0x7fffu + ((v.u >> 16) & 1u)) >> 16;
  return (short)r;
}
__device__ __forceinline__ float bf2f(short s) {
  union { unsigned u; float f; } v;
  v.u = ((unsigned)(unsigned short)s) << 16;
  return v.f;
}

__device__ __forceinline__ void load_x_row(const float* __restrict__ x, long r,
                                           float* __restrict__ xr) {
  const float4* xp = reinterpret_cast<const float4*>(x + r * DMOD);
  float4 v0 = xp[0], v1 = xp[1], v2 = xp[2], v3 = xp[3];
  xr[0] = v0.x; xr[1] = v0.y; xr[2] = v0.z; xr[3] = v0.w;
  xr[4] = v1.x; xr[5] = v1.y; xr[6] = v1.z; xr[7] = v1.w;
  xr[8] = v2.x; xr[9] = v2.y; xr[10] = v2.z; xr[11] = v2.w;
  xr[12] = v3.x; xr[13] = v3.y; xr[14] = v3.z; xr[15] = v3.w;
}

// scalar xm (halo rows only): xm[32] = rmsnorm(x_row) @ ipw[:, 0:32]
__device__ __forceinline__ void inproj_xm(const float* __restrict__ x,
                                          const float* __restrict__ rms1w,
                                          const float* __restrict__ ipw, long r,
                                          float* __restrict__ xm) {
  float xr[16];
  load_x_row(x, r, xr);
  float ss = 0.f;
#pragma unroll
  for (int i = 0; i < 16; i++) ss += xr[i] * xr[i];
  float inv = rsqrtf(ss * (1.f / 16.f) + 1e-6f);
  float x0[16];
#pragma unroll
  for (int i = 0; i < 16; i++) x0[i] = xr[i] * inv * rms1w[i];
#pragma unroll
  for (int k = 0; k < 32; k++) xm[k] = 0.f;
#pragma unroll
  for (int i = 0; i < 16; i++) {
    float xi = x0[i];
#pragma unroll
    for (int k = 0; k < 32; k++) xm[k] = fmaf(xi, ipw[i * 64 + k], xm[k]);
  }
}

__device__ __forceinline__ f32x4 mm(bf16x8 a, bf16x8 b, f32x4 c) {
  return __builtin_amdgcn_mfma_f32_16x16x32_bf16(a, b, c, 0, 0, 0);
}
__device__ __forceinline__ bf16x8 bfrag(const float* __restrict__ W, int ldw,
                                        int coloff, int col, int kg, int kreal) {
  bf16x8 b = {0, 0, 0, 0, 0, 0, 0, 0};
#pragma unroll
  for (int e = 0; e < 8; e++) {
    int k = kg * 8 + e;
    if (k < kreal) b[e] = f2bf(W[k * ldw + coloff + col]);
  }
  return b;
}

// ---- K1: MFMA prep + fused per-chunk local scan.  256 rows (4 chunks)/block.
// rec[chunk][c][64], c: dt[0:32) xc[32:64) B[64:80) C[80:96)
__global__ __launch_bounds__(256) void k_prep(
    const float* __restrict__ x, const float* __restrict__ rms1w,
    const float* __restrict__ ipw, const float* __restrict__ cw,
    const float* __restrict__ cb, const float* __restrict__ xpw,
    const float* __restrict__ dtw, const float* __restrict__ dtb,
    const float* __restrict__ A_log, float* __restrict__ rec,
    float* __restrict__ Pb, float* __restrict__ Hb) {
  __shared__ short x0b[259][40];   // x0 bf16 (+3 halo); later dts bf16 rows 0..255
  __shared__ float xmv[259][33];   // xm f32 (+halo); reused as proj[256][33]
  __shared__ short xcb[256][40];   // xc bf16
  int t = threadIdx.x;
  int lane = t & 63, wid = t >> 6;
  int col = lane & 15, kg = lane >> 4;
  long row0 = (long)blockIdx.x * 256;
  int l0 = (int)(row0 & (LSEQ - 1));
  const f32x4 zero4 = {0.f, 0.f, 0.f, 0.f};

  // weight fragments (once)
  bf16x8 Bip0 = bfrag(ipw, 64, 0, col, kg, 16);
  bf16x8 Bip1 = bfrag(ipw, 64, 16, col, kg, 16);
  bf16x8 Bdt, Bb, Bc;
#pragma unroll
  for (int e = 0; e < 8; e++) {
    int k = kg * 8 + e;
    Bdt[e] = (col == 0) ? f2bf(xpw[k * 33]) : (short)0;
    Bb[e] = f2bf(xpw[k * 33 + 1 + col]);
    Bc[e] = f2bf(xpw[k * 33 + 17 + col]);
  }

  // Phase A: rmsnorm -> x0 (bf16 to LDS); 3 halo xm rows scalar
  {
    float xr[16];
    load_x_row(x, row0 + t, xr);
    float ss = 0.f;
#pragma unroll
    for (int i = 0; i < 16; i++) ss += xr[i] * xr[i];
    float inv1 = rsqrtf(ss * (1.f / 16.f) + 1e-6f);
#pragma unroll
    for (int i = 0; i < 4; i++) {
      float a0 = xr[i * 4 + 0] * inv1 * rms1w[i * 4 + 0];
      float a1 = xr[i * 4 + 1] * inv1 * rms1w[i * 4 + 1];
      float a2 = xr[i * 4 + 2] * inv1 * rms1w[i * 4 + 2];
      float a3 = xr[i * 4 + 3] * inv1 * rms1w[i * 4 + 3];
      unsigned u0 = ((unsigned)(unsigned short)f2bf(a0)) |
                    (((unsigned)(unsigned short)f2bf(a1)) << 16);
      unsigned u1 = ((unsigned)(unsigned short)f2bf(a2)) |
                    (((unsigned)(unsigned short)f2bf(a3)) << 16);
      *reinterpret_cast<uint2*>(&x0b[3 + t][i * 4]) = make_uint2(u0, u1);
    }
  }
  if (t < 3) {
    float xmh[32];
    if (l0 == 0) {
#pragma unroll
      for (int d = 0; d < 32; d++) xmh[d] = 0.f;
    } else {
      inproj_xm(x, rms1w, ipw, row0 - 3 + t, xmh);
    }
#pragma unroll
    for (int d = 0; d < 32; d++) xmv[t][d] = xmh[d];
  }
  __syncthreads();

  // Phase B: xm = x0 @ ipw[:, 0:32] via MFMA
  {
    int tile0 = wid * 64;
#pragma unroll
    for (int rt = 0; rt < 4; rt++) {
      int arow = 3 + tile0 + rt * 16 + col;
      bf16x8 a = {0, 0, 0, 0, 0, 0, 0, 0};
      if (kg < 2) a = *reinterpret_cast<const bf16x8*>(&x0b[arow][kg * 8]);
      f32x4 m0 = mm(a, Bip0, zero4);
      f32x4 m1 = mm(a, Bip1, zero4);
      int orow = 3 + tile0 + rt * 16 + kg * 4;
#pragma unroll
      for (int reg = 0; reg < 4; reg++) {
        xmv[orow + reg][col] = m0[reg];
        xmv[orow + reg][col + 16] = m1[reg];
      }
    }
  }
  __syncthreads();

  // Phase C: causal conv + silu (f32, thread-per-row)
  float xc[32];
#pragma unroll
  for (int d = 0; d < 32; d++) {
    float c = cb[d];
#pragma unroll
    for (int k = 0; k < 4; k++) c = fmaf(cw[d * 4 + k], xmv[t + k][d], c);
    xc[d] = fsilu(c);
  }
#pragma unroll
  for (int i = 0; i < 8; i++) {
    unsigned u0 = ((unsigned)(unsigned short)f2bf(xc[i * 4 + 0])) |
                  (((unsigned)(unsigned short)f2bf(xc[i * 4 + 1])) << 16);
    unsigned u1 = ((unsigned)(unsigned short)f2bf(xc[i * 4 + 2])) |
                  (((unsigned)(unsigned short)f2bf(xc[i * 4 + 3])) << 16);
    *reinterpret_cast<uint2*>(&xcb[t][i * 4]) = make_uint2(u0, u1);
  }
  __syncthreads();

  // Phase D: proj = xc @ xpw via MFMA (dt col 0, B cols 1..16, C cols 17..32)
  float* prj = &xmv[0][0];  // reuse (stride 33), rows 0..255
  {
    int tile0 = wid * 64;
#pragma unroll
    for (int rt = 0; rt < 4; rt++) {
      int arow = tile0 + rt * 16 + col;
      bf16x8 a2 = *reinterpret_cast<const bf16x8*>(&xcb[arow][kg * 8]);
      f32x4 pd = mm(a2, Bdt, zero4);
      f32x4 pb = mm(a2, Bb, zero4);
      f32x4 pc = mm(a2, Bc, zero4);
      int orow = tile0 + rt * 16 + kg * 4;
#pragma unroll
      for (int reg = 0; reg < 4; reg++) {
        if (col == 0) prj[(orow + reg) * 33] = pd[reg];
        prj[(orow + reg) * 33 + 1 + col] = pb[reg];
        prj[(orow + reg) * 33 + 17 + col] = pc[reg];
      }
    }
  }
  __syncthreads();

  // Phase E: coalesced comp-major global writes; park dt (bf16) in x0b rows
  {
    int ch = t >> 6, l = t & 63;
    float* base = rec + (size_t)(blockIdx.x * 4 + ch) * CHF;
    float p0 = prj[t * 33];
    unsigned* dtrow = reinterpret_cast<unsigned*>(&x0b[t][0]);
#pragma unroll
    for (int d = 0; d < 32; d += 2) {
      float dv0 = fsoftplus(p0 * dtw[d] + dtb[d]);
      float dv1 = fsoftplus(p0 * dtw[d + 1] + dtb[d + 1]);
      base[d * 64 + l] = dv0;
      base[(d + 1) * 64 + l] = dv1;
      base[(32 + d) * 64 + l] = xc[d];
      base[(33 + d) * 64 + l] = xc[d + 1];
      dtrow[d >> 1] = ((unsigned)(unsigned short)f2bf(dv0)) |
                      (((unsigned)(unsigned short)f2bf(dv1)) << 16);
    }
#pragma unroll
    for (int i = 0; i < 16; i++) {
      base[(64 + i) * 64 + l] = prj[t * 33 + 1 + i];
      base[(80 + i) * 64 + l] = prj[t * 33 + 17 + i];
    }
  }
  __syncthreads();

  // Phase F: per-chunk local scan -> P (decay), H (state from h0=0)
  {
    int b128 = t & 127;
    int grp = t >> 7;
    int d = b128 >> 2, s4 = (b128 & 3) << 2;
    float4 al = *reinterpret_cast<const float4*>(A_log + d * DSTA + s4);
    float Ad[4] = {-__expf(al.x), -__expf(al.y), -__expf(al.z), -__expf(al.w)};
#pragma unroll 1
    for (int ci = 0; ci < 2; ci++) {
      int ch = grp * 2 + ci;
      float H[4] = {0.f, 0.f, 0.f, 0.f};
      float sumdt = 0.f;
#pragma unroll 4
      for (int li = 0; li < CL; li++) {
        int row = ch * 64 + li;
        float dt = bf2f(x0b[row][d]);
        float xcv = bf2f(xcb[row][d]);
        float dx = dt * xcv;
        sumdt += dt;
        const float* pr = &xmv[row][1 + s4];
        float a;
        a = __expf(dt * Ad[0]); H[0] = fmaf(a, H[0], dx * pr[0]);
        a = __expf(dt * Ad[1]); H[1] = fmaf(a, H[1], dx * pr[1]);
        a = __expf(dt * Ad[2]); H[2] = fmaf(a, H[2], dx * pr[2]);
        a = __expf(dt * Ad[3]); H[3] = fmaf(a, H[3], dx * pr[3]);
      }
      size_t base = (size_t)(blockIdx.x * 4 + ch) * 512 + (size_t)(d * 16 + s4);
      *reinterpret_cast<float4*>(Pb + base) =
          make_float4(__expf(sumdt * Ad[0]), __expf(sumdt * Ad[1]),
                      __expf(sumdt * Ad[2]), __expf(sumdt * Ad[3]));
      *reinterpret_cast<float4*>(Hb + base) =
          make_float4(H[0], H[1], H[2], H[3]);
    }
  }
}

// ---- K2a: segmented scan (4 segments x 32 chunks) with prefix products
__global__ __launch_bounds__(256) void k_seg(const float* __restrict__ Pb,
                                             const float* __restrict__ Hb,
                                             float* __restrict__ hs,
                                             float* __restrict__ prod,
                                             float* __restrict__ segP,
                                             float* __restrict__ segH) {
  int g = blockIdx.x * 256 + threadIdx.x;  // 32768
  int b = g >> 11;
  int rem = g & 2047;
  int seg = rem >> 9, st = rem & 511;
  size_t o = ((size_t)(b * NCH + seg * 32)) * 512 + st;
  float h = 0.f, p = 1.f;
#pragma unroll 4
  for (int c = 0; c < 32; c++) {
    hs[o] = h;
    prod[o] = p;
    float P = Pb[o], H = Hb[o];
    h = fmaf(P, h, H);
    p *= P;
    o += 512;
  }
  size_t so = (size_t)(b * 4 + seg) * 512 + st;
  segP[so] = p;
  segH[so] = h;
}

// ---- K2b: scan over the 4 segment summaries -> segment start states
__global__ __launch_bounds__(256) void k_carry(const float* __restrict__ segP,
                                               const float* __restrict__ segH,
                                               float* __restrict__ carry) {
  int g = blockIdx.x * 256 + threadIdx.x;  // 8192
  int b = g >> 9, st = g & 511;
  float h = 0.f;
#pragma unroll
  for (int s = 0; s < 4; s++) {
    size_t so = (size_t)(b * 4 + s) * 512 + st;
    carry[so] = h;
    h = fmaf(segP[so], h, segH[so]);
  }
}

// ---- K3: fused per-chunk scan + MFMA epilogue
__device__ __forceinline__ bf16x8 afrag(const float* sb, int lrow, int kg,
                                        int kreal) {
  bf16x8 a = {0, 0, 0, 0, 0, 0, 0, 0};
  if (kg * 8 < kreal) {
    const float4* p = reinterpret_cast<const float4*>(sb + lrow * 36 + kg * 8);
    float4 u = p[0], v = p[1];
    a[0] = f2bf(u.x); a[1] = f2bf(u.y); a[2] = f2bf(u.z); a[3] = f2bf(u.w);
    a[4] = f2bf(v.x); a[5] = f2bf(v.y); a[6] = f2bf(v.z); a[7] = f2bf(v.w);
  }
  return a;
}

__global__ __launch_bounds__(128) void k_scanmlp(
    const float* __restrict__ rec, const float* __restrict__ x,
    const float* __restrict__ A_log, const float* __restrict__ hs,
    const float* __restrict__ prod, const float* __restrict__ carry,
    const float* __restrict__ rms1w, const float* __restrict__ ipw,
    const float* __restrict__ Dskip, const float* __restrict__ opw,
    const float* __restrict__ rms2w, const float* __restrict__ f1w,
    const float* __restrict__ f1b, const float* __restrict__ f2w,
    const float* __restrict__ f2b, const float* __restrict__ f3w,
    const float* __restrict__ f3b, float* __restrict__ out) {
  __shared__ float sm[96 * 65];
  __shared__ float sb[64 * 36];
  __shared__ short x0b[64][24];
  int t = threadIdx.x, bc = blockIdx.x;
  const float* cbase = rec + (size_t)bc * CHF;
#pragma unroll
  for (int i = 0; i < 12; i++) {
    int g4 = i * 512 + t * 4;
    int c = g4 >> 6, l = g4 & 63;
    *reinterpret_cast<float4*>(&sm[c * 65 + l]) =
        *reinterpret_cast<const float4*>(cbase + g4);
  }
  if (t < 64) {
    float xr[16];
    load_x_row(x, (long)bc * CL + t, xr);
    float ss = 0.f;
#pragma unroll
    for (int i = 0; i < 16; i++) ss += xr[i] * xr[i];
    float inv1 = rsqrtf(ss * (1.f / 16.f) + 1e-6f);
#pragma unroll
    for (int i = 0; i < 4; i++) {
      float a0 = xr[i * 4 + 0] * inv1 * rms1w[i * 4 + 0];
      float a1 = xr[i * 4 + 1] * inv1 * rms1w[i * 4 + 1];
      float a2 = xr[i * 4 + 2] * inv1 * rms1w[i * 4 + 2];
      float a3 = xr[i * 4 + 3] * inv1 * rms1w[i * 4 + 3];
      unsigned u0 = ((unsigned)(unsigned short)f2bf(a0)) |
                    (((unsigned)(unsigned short)f2bf(a1)) << 16);
      unsigned u1 = ((unsigned)(unsigned short)f2bf(a2)) |
                    (((unsigned)(unsigned short)f2bf(a3)) << 16);
      *reinterpret_cast<uint2*>(&x0b[t][i * 4]) = make_uint2(u0, u1);
    }
  }
  __syncthreads();

  // scan; y overwrites the dead dt slot (wave-partitioned by d)
  {
    int d = t >> 2, s4 = (t & 3) << 2;
    float4 al = *reinterpret_cast<const float4*>(A_log + d * DSTA + s4);
    float Ad[4] = {-__expf(al.x), -__expf(al.y), -__expf(al.z), -__expf(al.w)};
    float h[4];
    {
      size_t hoff = (size_t)bc * 512 + (size_t)(d * 16 + s4);
      float4 hl = *reinterpret_cast<const float4*>(hs + hoff);
      float4 pr = *reinterpret_cast<const float4*>(prod + hoff);
      int b = bc >> 7, seg = (bc >> 5) & 3;
      float4 cr = *reinterpret_cast<const float4*>(
          carry + (size_t)(b * 4 + seg) * 512 + (size_t)(d * 16 + s4));
      h[0] = fmaf(pr.x, cr.x, hl.x);
      h[1] = fmaf(pr.y, cr.y, hl.y);
      h[2] = fmaf(pr.z, cr.z, hl.z);
      h[3] = fmaf(pr.w, cr.w, hl.w);
    }
    int dof = d * 65, xof = (32 + d) * 65;
    int bof0 = (64 + s4) * 65, bof1 = (65 + s4) * 65, bof2 = (66 + s4) * 65,
        bof3 = (67 + s4) * 65;
    int cof0 = (80 + s4) * 65, cof1 = (81 + s4) * 65, cof2 = (82 + s4) * 65,
        cof3 = (83 + s4) * 65;
    bool wy = (t & 3) == 0;
#pragma unroll 2
    for (int l = 0; l < CL; l++) {
      float dt = sm[dof + l];
      float xcv = sm[xof + l];
      float dx = dt * xcv;
      float a;
      a = __expf(dt * Ad[0]); h[0] = fmaf(a, h[0], dx * sm[bof0 + l]);
      a = __expf(dt * Ad[1]); h[1] = fmaf(a, h[1], dx * sm[bof1 + l]);
      a = __expf(dt * Ad[2]); h[2] = fmaf(a, h[2], dx * sm[bof2 + l]);
      a = __expf(dt * Ad[3]); h[3] = fmaf(a, h[3], dx * sm[bof3 + l]);
      float y = sm[cof0 + l] * h[0];
      y = fmaf(sm[cof1 + l], h[1], y);
      y = fmaf(sm[cof2 + l], h[2], y);
      y = fmaf(sm[cof3 + l], h[3], y);
      y += __shfl_xor(y, 1);
      y += __shfl_xor(y, 2);
      if (wy) sm[dof + l] = y;
    }
  }
  __syncthreads();

  // MFMA epilogue: 2 waves x 32 rows
  {
    int lane = t & 63, w = t >> 6;
    int col = lane & 15, kg = lane >> 4;
    bf16x8 Bz0 = bfrag(ipw + 32, 64, 0, col, kg, 16);
    bf16x8 Bz1 = bfrag(ipw + 32, 64, 16, col, kg, 16);
    bf16x8 Bop = bfrag(opw, 16, 0, col, kg, 32);
    bf16x8 Bf1_0 = bfrag(f1w, 32, 0, col, kg, 16);
    bf16x8 Bf1_1 = bfrag(f1w, 32, 16, col, kg, 16);
    bf16x8 Bf2_0 = bfrag(f2w, 32, 0, col, kg, 32);
    bf16x8 Bf2_1 = bfrag(f2w, 32, 16, col, kg, 32);
    bf16x8 Bf3 = bfrag(f3w, 16, 0, col, kg, 32);
    float b1_0 = f1b[col], b1_1 = f1b[16 + col];
    float b2_0 = f2b[col], b2_1 = f2b[16 + col];
    float b3_c = f3b[col];
    float dsk0 = Dskip[col], dsk1 = Dskip[16 + col];
    float rw2 = rms2w[col];
    const f32x4 zero4 = {0.f, 0.f, 0.f, 0.f};
    long rowbase = (long)bc * CL;
#pragma unroll 1
    for (int rt = 0; rt < 2; rt++) {
      int tile0 = w * 32 + rt * 16;
      bf16x8 ax0 = {0, 0, 0, 0, 0, 0, 0, 0};
      if (kg < 2)
        ax0 = *reinterpret_cast<const bf16x8*>(&x0b[tile0 + col][kg * 8]);
      f32x4 zf0 = mm(ax0, Bz0, zero4);
      f32x4 zf1 = mm(ax0, Bz1, zero4);
#pragma unroll
      for (int reg = 0; reg < 4; reg++) {
        int lrow = tile0 + kg * 4 + reg;
        float y0 = sm[col * 65 + lrow];
        float y1 = sm[(16 + col) * 65 + lrow];
        float xc0 = sm[(32 + col) * 65 + lrow];
        float xc1 = sm[(48 + col) * 65 + lrow];
        sb[lrow * 36 + col] = (y0 + dsk0 * xc0) * fsilu(zf0[reg]);
        sb[lrow * 36 + 16 + col] = (y1 + dsk1 * xc1) * fsilu(zf1[reg]);
      }
      bf16x8 ayo = afrag(sb, tile0 + col, kg, 32);
      f32x4 x1f = mm(ayo, Bop, zero4);
      float xres[4];
#pragma unroll
      for (int reg = 0; reg < 4; reg++) {
        long grow = rowbase + tile0 + kg * 4 + reg;
        xres[reg] = x1f[reg] + x[grow * 16 + col];
      }
#pragma unroll
      for (int reg = 0; reg < 4; reg++) {
        float ss = xres[reg] * xres[reg];
        ss += __shfl_xor(ss, 1);
        ss += __shfl_xor(ss, 2);
        ss += __shfl_xor(ss, 4);
        ss += __shfl_xor(ss, 8);
        float inv2 = rsqrtf(ss * (1.f / 16.f) + 1e-6f);
        sb[(tile0 + kg * 4 + reg) * 36 + col] = xres[reg] * inv2 * rw2;
      }
      bf16x8 ax2 = afrag(sb, tile0 + col, kg, 16);
      f32x4 h1f0 = mm(ax2, Bf1_0, zero4);
      f32x4 h1f1 = mm(ax2, Bf1_1, zero4);
#pragma unroll
      for (int reg = 0; reg < 4; reg++) {
        int lrow = tile0 + kg * 4 + reg;
        sb[lrow * 36 + col] = fmaxf(h1f0[reg] + b1_0, 0.f);
        sb[lrow * 36 + 16 + col] = fmaxf(h1f1[reg] + b1_1, 0.f);
      }
      bf16x8 ah1 = afrag(sb, tile0 + col, kg, 32);
      f32x4 h2f0 = mm(ah1, Bf2_0, zero4);
      f32x4 h2f1 = mm(ah1, Bf2_1, zero4);
#pragma unroll
      for (int reg = 0; reg < 4; reg++) {
        int lrow = tile0 + kg * 4 + reg;
        sb[lrow * 36 + col] = fmaxf(h2f0[reg] + b2_0, 0.f);
        sb[lrow * 36 + 16 + col] = fmaxf(h2f1[reg] + b2_1, 0.f);
      }
      bf16x8 ah2 = afrag(sb, tile0 + col, kg, 32);
      f32x4 x3f = mm(ah2, Bf3, zero4);
#pragma unroll
      for (int reg = 0; reg < 4; reg++) {
        long grow = rowbase + tile0 + kg * 4 + reg;
        out[grow * 16 + col] = xres[reg] + x3f[reg] + b3_c;
      }
    }
  }
}

extern "C" void kernel_launch(void* const* d_in, const int* in_sizes, int n_in,
                              void* d_out, int out_size, void* d_ws,
                              size_t ws_size, hipStream_t stream) {
  const float* x = (const float*)d_in[0];
  const float* rms1w = (const float*)d_in[1];
  const float* ipw = (const float*)d_in[2];
  const float* cw = (const float*)d_in[3];
  const float* cb = (const float*)d_in[4];
  const float* xpw = (const float*)d_in[5];
  const float* dtw = (const float*)d_in[6];
  const float* dtb = (const float*)d_in[7];
  const float* A_log = (const float*)d_in[8];
  const float* Dskip = (const float*)d_in[9];
  const float* opw = (const float*)d_in[10];
  const float* rms2w = (const float*)d_in[11];
  const float* f1w = (const float*)d_in[12];
  const float* f1b = (const float*)d_in[13];
  const float* f2w = (const float*)d_in[14];
  const float* f2b = (const float*)d_in[15];
  const float* f3w = (const float*)d_in[16];
  const float* f3b = (const float*)d_in[17];
  float* out = (float*)d_out;

  float* rec = (float*)d_ws;                  // 50.3 MiB
  float* Pb = rec + (size_t)NCHT * CHF;       // 4 MiB
  float* Hb = Pb + SUMN;                      // 4 MiB
  float* hsb = Hb + SUMN;                     // 4 MiB
  float* prodb = hsb + SUMN;                  // 4 MiB
  float* segP = prodb + SUMN;                 // 128 KiB
  float* segH = segP + NBAT * 4 * 512;        // 128 KiB
  float* carry = segH + NBAT * 4 * 512;       // 128 KiB

  hipLaunchKernelGGL(k_prep, dim3(NROWS / 256), dim3(256), 0, stream, x, rms1w,
                     ipw, cw, cb, xpw, dtw, dtb, A_log, rec, Pb, Hb);
  hipLaunchKernelGGL(k_seg, dim3(128), dim3(256), 0, stream, Pb, Hb, hsb,
                     prodb, segP, segH);
  hipLaunchKernelGGL(k_carry, dim3(32), dim3(256), 0, stream, segP, segH,
                     carry);
  hipLaunchKernelGGL(k_scanmlp, dim3(NCHT), dim3(128), 0, stream, rec, x,
                     A_log, hsb, prodb, carry, rms1w, ipw, Dskip, opw, rms2w,
                     f1w, f1b, f2w, f2b, f3w, f3b, out);
}

// Round 8
// 96.060 us; speedup vs baseline: 1.8927x; 1.2289x over previous
//
#include <hip/hip_runtime.h>

#define LSEQ 8192
#define NBAT 16
#define DMOD 16
#define DINN 32
#define DSTA 16
#define CL   32
#define NCH  (LSEQ / CL)            // 256
#define NCHT (NBAT * NCH)           // 4096
#define CHF  (96 * CL)              // 3072 floats per chunk record (comp-major)
#define NROWS (NBAT * LSEQ)         // 131072
#define SUMN ((size_t)NCHT * 512)
#define NSEG 8
#define SEGC (NCH / NSEG)           // 32

typedef __attribute__((ext_vector_type(8))) short bf16x8;
typedef __attribute__((ext_vector_type(4))) float f32x4;

__device__ __forceinline__ float fsilu(float v) { return v / (1.f + __expf(-v)); }
__device__ __forceinline__ float fsoftplus(float v) {
  return v > 20.f ? v : __logf(1.f + __expf(v));
}
__device__ __forceinline__ short f2bf(float f) {
  union { float f; unsigned u; } v; v.f = f;
  unsigned r = (v.u + 0x7fffu + ((v.u >> 16) & 1u)) >> 16;
  return (short)r;
}
__device__ __forceinline__ float bf2f(short s) {
  union { unsigned u; float f; } v;
  v.u = ((unsigned)(unsigned short)s) << 16;
  return v.f;
}

__device__ __forceinline__ void load_x_row(const float* __restrict__ x, long r,
                                           float* __restrict__ xr) {
  const float4* xp = reinterpret_cast<const float4*>(x + r * DMOD);
  float4 v0 = xp[0], v1 = xp[1], v2 = xp[2], v3 = xp[3];
  xr[0] = v0.x; xr[1] = v0.y; xr[2] = v0.z; xr[3] = v0.w;
  xr[4] = v1.x; xr[5] = v1.y; xr[6] = v1.z; xr[7] = v1.w;
  xr[8] = v2.x; xr[9] = v2.y; xr[10] = v2.z; xr[11] = v2.w;
  xr[12] = v3.x; xr[13] = v3.y; xr[14] = v3.z; xr[15] = v3.w;
}

// scalar xm (halo rows only): xm[32] = rmsnorm(x_row) @ ipw[:, 0:32]
__device__ __forceinline__ void inproj_xm(const float* __restrict__ x,
                                          const float* __restrict__ rms1w,
                                          const float* __restrict__ ipw, long r,
                                          float* __restrict__ xm) {
  float xr[16];
  load_x_row(x, r, xr);
  float ss = 0.f;
#pragma unroll
  for (int i = 0; i < 16; i++) ss += xr[i] * xr[i];
  float inv = rsqrtf(ss * (1.f / 16.f) + 1e-6f);
  float x0[16];
#pragma unroll
  for (int i = 0; i < 16; i++) x0[i] = xr[i] * inv * rms1w[i];
#pragma unroll
  for (int k = 0; k < 32; k++) xm[k] = 0.f;
#pragma unroll
  for (int i = 0; i < 16; i++) {
    float xi = x0[i];
#pragma unroll
    for (int k = 0; k < 32; k++) xm[k] = fmaf(xi, ipw[i * 64 + k], xm[k]);
  }
}

__device__ __forceinline__ f32x4 mm(bf16x8 a, bf16x8 b, f32x4 c) {
  return __builtin_amdgcn_mfma_f32_16x16x32_bf16(a, b, c, 0, 0, 0);
}
__device__ __forceinline__ bf16x8 bfrag(const float* __restrict__ W, int ldw,
                                        int coloff, int col, int kg, int kreal) {
  bf16x8 b = {0, 0, 0, 0, 0, 0, 0, 0};
#pragma unroll
  for (int e = 0; e < 8; e++) {
    int k = kg * 8 + e;
    if (k < kreal) b[e] = f2bf(W[k * ldw + coloff + col]);
  }
  return b;
}

// ---- K1: MFMA prep + fused per-chunk local scan.  256 rows (8 chunks)/block.
// rec[chunk][c][32], c: dt[0:32) xc[32:64) B[64:80) C[80:96)
__global__ __launch_bounds__(256) void k_prep(
    const float* __restrict__ x, const float* __restrict__ rms1w,
    const float* __restrict__ ipw, const float* __restrict__ cw,
    const float* __restrict__ cb, const float* __restrict__ xpw,
    const float* __restrict__ dtw, const float* __restrict__ dtb,
    const float* __restrict__ A_log, float* __restrict__ rec,
    float* __restrict__ Pb, float* __restrict__ Hb) {
  __shared__ short x0b[259][40];   // x0 bf16 (+3 halo); later dt bf16 rows 0..255
  __shared__ float xmv[259][33];   // xm f32 (+halo); reused as proj[256][33]
  __shared__ short xcb[256][40];   // xc bf16
  int t = threadIdx.x;
  int lane = t & 63, wid = t >> 6;
  int col = lane & 15, kg = lane >> 4;
  long row0 = (long)blockIdx.x * 256;
  int l0 = (int)(row0 & (LSEQ - 1));
  const f32x4 zero4 = {0.f, 0.f, 0.f, 0.f};

  bf16x8 Bip0 = bfrag(ipw, 64, 0, col, kg, 16);
  bf16x8 Bip1 = bfrag(ipw, 64, 16, col, kg, 16);
  bf16x8 Bdt, Bb, Bc;
#pragma unroll
  for (int e = 0; e < 8; e++) {
    int k = kg * 8 + e;
    Bdt[e] = (col == 0) ? f2bf(xpw[k * 33]) : (short)0;
    Bb[e] = f2bf(xpw[k * 33 + 1 + col]);
    Bc[e] = f2bf(xpw[k * 33 + 17 + col]);
  }

  // Phase A: rmsnorm -> x0 (bf16 to LDS); 3 halo xm rows scalar
  {
    float xr[16];
    load_x_row(x, row0 + t, xr);
    float ss = 0.f;
#pragma unroll
    for (int i = 0; i < 16; i++) ss += xr[i] * xr[i];
    float inv1 = rsqrtf(ss * (1.f / 16.f) + 1e-6f);
#pragma unroll
    for (int i = 0; i < 4; i++) {
      float a0 = xr[i * 4 + 0] * inv1 * rms1w[i * 4 + 0];
      float a1 = xr[i * 4 + 1] * inv1 * rms1w[i * 4 + 1];
      float a2 = xr[i * 4 + 2] * inv1 * rms1w[i * 4 + 2];
      float a3 = xr[i * 4 + 3] * inv1 * rms1w[i * 4 + 3];
      unsigned u0 = ((unsigned)(unsigned short)f2bf(a0)) |
                    (((unsigned)(unsigned short)f2bf(a1)) << 16);
      unsigned u1 = ((unsigned)(unsigned short)f2bf(a2)) |
                    (((unsigned)(unsigned short)f2bf(a3)) << 16);
      *reinterpret_cast<uint2*>(&x0b[3 + t][i * 4]) = make_uint2(u0, u1);
    }
  }
  if (t < 3) {
    float xmh[32];
    if (l0 == 0) {
#pragma unroll
      for (int d = 0; d < 32; d++) xmh[d] = 0.f;
    } else {
      inproj_xm(x, rms1w, ipw, row0 - 3 + t, xmh);
    }
#pragma unroll
    for (int d = 0; d < 32; d++) xmv[t][d] = xmh[d];
  }
  __syncthreads();

  // Phase B: xm = x0 @ ipw[:, 0:32] via MFMA
  {
    int tile0 = wid * 64;
#pragma unroll
    for (int rt = 0; rt < 4; rt++) {
      int arow = 3 + tile0 + rt * 16 + col;
      bf16x8 a = {0, 0, 0, 0, 0, 0, 0, 0};
      if (kg < 2) a = *reinterpret_cast<const bf16x8*>(&x0b[arow][kg * 8]);
      f32x4 m0 = mm(a, Bip0, zero4);
      f32x4 m1 = mm(a, Bip1, zero4);
      int orow = 3 + tile0 + rt * 16 + kg * 4;
#pragma unroll
      for (int reg = 0; reg < 4; reg++) {
        xmv[orow + reg][col] = m0[reg];
        xmv[orow + reg][col + 16] = m1[reg];
      }
    }
  }
  __syncthreads();

  // Phase C: causal conv + silu (f32, thread-per-row)
  float xc[32];
#pragma unroll
  for (int d = 0; d < 32; d++) {
    float c = cb[d];
#pragma unroll
    for (int k = 0; k < 4; k++) c = fmaf(cw[d * 4 + k], xmv[t + k][d], c);
    xc[d] = fsilu(c);
  }
#pragma unroll
  for (int i = 0; i < 8; i++) {
    unsigned u0 = ((unsigned)(unsigned short)f2bf(xc[i * 4 + 0])) |
                  (((unsigned)(unsigned short)f2bf(xc[i * 4 + 1])) << 16);
    unsigned u1 = ((unsigned)(unsigned short)f2bf(xc[i * 4 + 2])) |
                  (((unsigned)(unsigned short)f2bf(xc[i * 4 + 3])) << 16);
    *reinterpret_cast<uint2*>(&xcb[t][i * 4]) = make_uint2(u0, u1);
  }
  __syncthreads();

  // Phase D: proj = xc @ xpw via MFMA (dt col 0, B cols 1..16, C cols 17..32)
  float* prj = &xmv[0][0];  // reuse (stride 33), rows 0..255
  {
    int tile0 = wid * 64;
#pragma unroll
    for (int rt = 0; rt < 4; rt++) {
      int arow = tile0 + rt * 16 + col;
      bf16x8 a2 = *reinterpret_cast<const bf16x8*>(&xcb[arow][kg * 8]);
      f32x4 pd = mm(a2, Bdt, zero4);
      f32x4 pb = mm(a2, Bb, zero4);
      f32x4 pc = mm(a2, Bc, zero4);
      int orow = tile0 + rt * 16 + kg * 4;
#pragma unroll
      for (int reg = 0; reg < 4; reg++) {
        if (col == 0) prj[(orow + reg) * 33] = pd[reg];
        prj[(orow + reg) * 33 + 1 + col] = pb[reg];
        prj[(orow + reg) * 33 + 17 + col] = pc[reg];
      }
    }
  }
  __syncthreads();

  // Phase E: coalesced comp-major global writes; park dt (bf16) in x0b rows
  {
    int ch = t >> 5, l = t & 31;
    float* base = rec + (size_t)(blockIdx.x * 8 + ch) * CHF;
    float p0 = prj[t * 33];
    unsigned* dtrow = reinterpret_cast<unsigned*>(&x0b[t][0]);
#pragma unroll
    for (int d = 0; d < 32; d += 2) {
      float dv0 = fsoftplus(p0 * dtw[d] + dtb[d]);
      float dv1 = fsoftplus(p0 * dtw[d + 1] + dtb[d + 1]);
      base[d * 32 + l] = dv0;
      base[(d + 1) * 32 + l] = dv1;
      base[(32 + d) * 32 + l] = xc[d];
      base[(33 + d) * 32 + l] = xc[d + 1];
      dtrow[d >> 1] = ((unsigned)(unsigned short)f2bf(dv0)) |
                      (((unsigned)(unsigned short)f2bf(dv1)) << 16);
    }
#pragma unroll
    for (int i = 0; i < 16; i++) {
      base[(64 + i) * 32 + l] = prj[t * 33 + 1 + i];
      base[(80 + i) * 32 + l] = prj[t * 33 + 17 + i];
    }
  }
  __syncthreads();

  // Phase F: per-chunk local scan -> P (decay), H (state from h0=0)
  {
    int b128 = t & 127;
    int grp = t >> 7;
    int d = b128 >> 2, s4 = (b128 & 3) << 2;
    float4 al = *reinterpret_cast<const float4*>(A_log + d * DSTA + s4);
    float Ad[4] = {-__expf(al.x), -__expf(al.y), -__expf(al.z), -__expf(al.w)};
#pragma unroll 1
    for (int ci = 0; ci < 4; ci++) {
      int ch = grp * 4 + ci;
      float H[4] = {0.f, 0.f, 0.f, 0.f};
      float sumdt = 0.f;
#pragma unroll 4
      for (int li = 0; li < CL; li++) {
        int row = ch * CL + li;
        float dt = bf2f(x0b[row][d]);
        float xcv = bf2f(xcb[row][d]);
        float dx = dt * xcv;
        sumdt += dt;
        const float* pr = &xmv[row][1 + s4];
        float a;
        a = __expf(dt * Ad[0]); H[0] = fmaf(a, H[0], dx * pr[0]);
        a = __expf(dt * Ad[1]); H[1] = fmaf(a, H[1], dx * pr[1]);
        a = __expf(dt * Ad[2]); H[2] = fmaf(a, H[2], dx * pr[2]);
        a = __expf(dt * Ad[3]); H[3] = fmaf(a, H[3], dx * pr[3]);
      }
      size_t base = (size_t)(blockIdx.x * 8 + ch) * 512 + (size_t)(d * 16 + s4);
      *reinterpret_cast<float4*>(Pb + base) =
          make_float4(__expf(sumdt * Ad[0]), __expf(sumdt * Ad[1]),
                      __expf(sumdt * Ad[2]), __expf(sumdt * Ad[3]));
      *reinterpret_cast<float4*>(Hb + base) =
          make_float4(H[0], H[1], H[2], H[3]);
    }
  }
}

// ---- K2a: segmented exclusive scan IN PLACE (Pb -> prefix prod, Hb -> prefix
// state), segment summaries out.  8 segments x 32 chunks per batch.
__global__ __launch_bounds__(256) void k_seg(float* __restrict__ Pb,
                                             float* __restrict__ Hb,
                                             float* __restrict__ segP,
                                             float* __restrict__ segH) {
  int g = blockIdx.x * 256 + threadIdx.x;  // 65536
  int b = g >> 12;
  int rem = g & 4095;
  int seg = rem >> 9, st = rem & 511;
  size_t o = ((size_t)(b * NCH + seg * SEGC)) * 512 + st;
  float h = 0.f, p = 1.f;
#pragma unroll 4
  for (int c = 0; c < SEGC; c++) {
    float P = Pb[o], H = Hb[o];
    Pb[o] = p;
    Hb[o] = h;
    h = fmaf(P, h, H);
    p *= P;
    o += 512;
  }
  size_t so = (size_t)(b * NSEG + seg) * 512 + st;
  segP[so] = p;
  segH[so] = h;
}

// ---- K2b: scan over segment summaries -> segment start states
__global__ __launch_bounds__(256) void k_carry(const float* __restrict__ segP,
                                               const float* __restrict__ segH,
                                               float* __restrict__ carry) {
  int g = blockIdx.x * 256 + threadIdx.x;  // 8192
  int b = g >> 9, st = g & 511;
  float h = 0.f;
#pragma unroll
  for (int s = 0; s < NSEG; s++) {
    size_t so = (size_t)(b * NSEG + s) * 512 + st;
    carry[so] = h;
    h = fmaf(segP[so], h, segH[so]);
  }
}

// ---- K3: fused per-chunk scan + MFMA epilogue (32-row chunks)
__device__ __forceinline__ bf16x8 afrag(const float* sb, int lrow, int kg,
                                        int kreal) {
  bf16x8 a = {0, 0, 0, 0, 0, 0, 0, 0};
  if (kg * 8 < kreal) {
    const float4* p = reinterpret_cast<const float4*>(sb + lrow * 36 + kg * 8);
    float4 u = p[0], v = p[1];
    a[0] = f2bf(u.x); a[1] = f2bf(u.y); a[2] = f2bf(u.z); a[3] = f2bf(u.w);
    a[4] = f2bf(v.x); a[5] = f2bf(v.y); a[6] = f2bf(v.z); a[7] = f2bf(v.w);
  }
  return a;
}

__global__ __launch_bounds__(128) void k_scanmlp(
    const float* __restrict__ rec, const float* __restrict__ x,
    const float* __restrict__ A_log, const float* __restrict__ Hs,
    const float* __restrict__ Pr, const float* __restrict__ carry,
    const float* __restrict__ rms1w, const float* __restrict__ ipw,
    const float* __restrict__ Dskip, const float* __restrict__ opw,
    const float* __restrict__ rms2w, const float* __restrict__ f1w,
    const float* __restrict__ f1b, const float* __restrict__ f2w,
    const float* __restrict__ f2b, const float* __restrict__ f3w,
    const float* __restrict__ f3b, float* __restrict__ out) {
  __shared__ float sm[96 * 33];
  __shared__ float sb[32 * 36];
  __shared__ short x0b[32][24];
  int t = threadIdx.x, bc = blockIdx.x;
  const float* cbase = rec + (size_t)bc * CHF;
#pragma unroll
  for (int i = 0; i < 6; i++) {
    int g4 = i * 512 + t * 4;
    int c = g4 >> 5, l = g4 & 31;
    *reinterpret_cast<float4*>(&sm[c * 33 + l]) =
        *reinterpret_cast<const float4*>(cbase + g4);
  }
  if (t < CL) {
    float xr[16];
    load_x_row(x, (long)bc * CL + t, xr);
    float ss = 0.f;
#pragma unroll
    for (int i = 0; i < 16; i++) ss += xr[i] * xr[i];
    float inv1 = rsqrtf(ss * (1.f / 16.f) + 1e-6f);
#pragma unroll
    for (int i = 0; i < 4; i++) {
      float a0 = xr[i * 4 + 0] * inv1 * rms1w[i * 4 + 0];
      float a1 = xr[i * 4 + 1] * inv1 * rms1w[i * 4 + 1];
      float a2 = xr[i * 4 + 2] * inv1 * rms1w[i * 4 + 2];
      float a3 = xr[i * 4 + 3] * inv1 * rms1w[i * 4 + 3];
      unsigned u0 = ((unsigned)(unsigned short)f2bf(a0)) |
                    (((unsigned)(unsigned short)f2bf(a1)) << 16);
      unsigned u1 = ((unsigned)(unsigned short)f2bf(a2)) |
                    (((unsigned)(unsigned short)f2bf(a3)) << 16);
      *reinterpret_cast<uint2*>(&x0b[t][i * 4]) = make_uint2(u0, u1);
    }
  }
  __syncthreads();

  // scan; y overwrites the dead dt slot (wave-partitioned by d)
  {
    int d = t >> 2, s4 = (t & 3) << 2;
    float4 al = *reinterpret_cast<const float4*>(A_log + d * DSTA + s4);
    float Ad[4] = {-__expf(al.x), -__expf(al.y), -__expf(al.z), -__expf(al.w)};
    float h[4];
    {
      size_t hoff = (size_t)bc * 512 + (size_t)(d * 16 + s4);
      float4 hl = *reinterpret_cast<const float4*>(Hs + hoff);
      float4 pr = *reinterpret_cast<const float4*>(Pr + hoff);
      int b = bc >> 8, seg = (bc >> 5) & 7;
      float4 cr = *reinterpret_cast<const float4*>(
          carry + (size_t)(b * NSEG + seg) * 512 + (size_t)(d * 16 + s4));
      h[0] = fmaf(pr.x, cr.x, hl.x);
      h[1] = fmaf(pr.y, cr.y, hl.y);
      h[2] = fmaf(pr.z, cr.z, hl.z);
      h[3] = fmaf(pr.w, cr.w, hl.w);
    }
    int dof = d * 33, xof = (32 + d) * 33;
    int bof0 = (64 + s4) * 33, bof1 = (65 + s4) * 33, bof2 = (66 + s4) * 33,
        bof3 = (67 + s4) * 33;
    int cof0 = (80 + s4) * 33, cof1 = (81 + s4) * 33, cof2 = (82 + s4) * 33,
        cof3 = (83 + s4) * 33;
    bool wy = (t & 3) == 0;
#pragma unroll 4
    for (int l = 0; l < CL; l++) {
      float dt = sm[dof + l];
      float xcv = sm[xof + l];
      float dx = dt * xcv;
      float a;
      a = __expf(dt * Ad[0]); h[0] = fmaf(a, h[0], dx * sm[bof0 + l]);
      a = __expf(dt * Ad[1]); h[1] = fmaf(a, h[1], dx * sm[bof1 + l]);
      a = __expf(dt * Ad[2]); h[2] = fmaf(a, h[2], dx * sm[bof2 + l]);
      a = __expf(dt * Ad[3]); h[3] = fmaf(a, h[3], dx * sm[bof3 + l]);
      float y = sm[cof0 + l] * h[0];
      y = fmaf(sm[cof1 + l], h[1], y);
      y = fmaf(sm[cof2 + l], h[2], y);
      y = fmaf(sm[cof3 + l], h[3], y);
      y += __shfl_xor(y, 1);
      y += __shfl_xor(y, 2);
      if (wy) sm[dof + l] = y;
    }
  }
  __syncthreads();

  // MFMA epilogue: 2 waves x one 16-row tile each
  {
    int lane = t & 63, w = t >> 6;
    int col = lane & 15, kg = lane >> 4;
    bf16x8 Bz0 = bfrag(ipw + 32, 64, 0, col, kg, 16);
    bf16x8 Bz1 = bfrag(ipw + 32, 64, 16, col, kg, 16);
    bf16x8 Bop = bfrag(opw, 16, 0, col, kg, 32);
    bf16x8 Bf1_0 = bfrag(f1w, 32, 0, col, kg, 16);
    bf16x8 Bf1_1 = bfrag(f1w, 32, 16, col, kg, 16);
    bf16x8 Bf2_0 = bfrag(f2w, 32, 0, col, kg, 32);
    bf16x8 Bf2_1 = bfrag(f2w, 32, 16, col, kg, 32);
    bf16x8 Bf3 = bfrag(f3w, 16, 0, col, kg, 32);
    float b1_0 = f1b[col], b1_1 = f1b[16 + col];
    float b2_0 = f2b[col], b2_1 = f2b[16 + col];
    float b3_c = f3b[col];
    float dsk0 = Dskip[col], dsk1 = Dskip[16 + col];
    float rw2 = rms2w[col];
    const f32x4 zero4 = {0.f, 0.f, 0.f, 0.f};
    long rowbase = (long)bc * CL;
    int tile0 = w * 16;
    bf16x8 ax0 = {0, 0, 0, 0, 0, 0, 0, 0};
    if (kg < 2)
      ax0 = *reinterpret_cast<const bf16x8*>(&x0b[tile0 + col][kg * 8]);
    f32x4 zf0 = mm(ax0, Bz0, zero4);
    f32x4 zf1 = mm(ax0, Bz1, zero4);
#pragma unroll
    for (int reg = 0; reg < 4; reg++) {
      int lrow = tile0 + kg * 4 + reg;
      float y0 = sm[col * 33 + lrow];
      float y1 = sm[(16 + col) * 33 + lrow];
      float xc0 = sm[(32 + col) * 33 + lrow];
      float xc1 = sm[(48 + col) * 33 + lrow];
      sb[lrow * 36 + col] = (y0 + dsk0 * xc0) * fsilu(zf0[reg]);
      sb[lrow * 36 + 16 + col] = (y1 + dsk1 * xc1) * fsilu(zf1[reg]);
    }
    bf16x8 ayo = afrag(sb, tile0 + col, kg, 32);
    f32x4 x1f = mm(ayo, Bop, zero4);
    float xres[4];
#pragma unroll
    for (int reg = 0; reg < 4; reg++) {
      long grow = rowbase + tile0 + kg * 4 + reg;
      xres[reg] = x1f[reg] + x[grow * 16 + col];
    }
#pragma unroll
    for (int reg = 0; reg < 4; reg++) {
      float ss = xres[reg] * xres[reg];
      ss += __shfl_xor(ss, 1);
      ss += __shfl_xor(ss, 2);
      ss += __shfl_xor(ss, 4);
      ss += __shfl_xor(ss, 8);
      float inv2 = rsqrtf(ss * (1.f / 16.f) + 1e-6f);
      sb[(tile0 + kg * 4 + reg) * 36 + col] = xres[reg] * inv2 * rw2;
    }
    bf16x8 ax2 = afrag(sb, tile0 + col, kg, 16);
    f32x4 h1f0 = mm(ax2, Bf1_0, zero4);
    f32x4 h1f1 = mm(ax2, Bf1_1, zero4);
#pragma unroll
    for (int reg = 0; reg < 4; reg++) {
      int lrow = tile0 + kg * 4 + reg;
      sb[lrow * 36 + col] = fmaxf(h1f0[reg] + b1_0, 0.f);
      sb[lrow * 36 + 16 + col] = fmaxf(h1f1[reg] + b1_1, 0.f);
    }
    bf16x8 ah1 = afrag(sb, tile0 + col, kg, 32);
    f32x4 h2f0 = mm(ah1, Bf2_0, zero4);
    f32x4 h2f1 = mm(ah1, Bf2_1, zero4);
#pragma unroll
    for (int reg = 0; reg < 4; reg++) {
      int lrow = tile0 + kg * 4 + reg;
      sb[lrow * 36 + col] = fmaxf(h2f0[reg] + b2_0, 0.f);
      sb[lrow * 36 + 16 + col] = fmaxf(h2f1[reg] + b2_1, 0.f);
    }
    bf16x8 ah2 = afrag(sb, tile0 + col, kg, 32);
    f32x4 x3f = mm(ah2, Bf3, zero4);
#pragma unroll
    for (int reg = 0; reg < 4; reg++) {
      long grow = rowbase + tile0 + kg * 4 + reg;
      out[grow * 16 + col] = xres[reg] + x3f[reg] + b3_c;
    }
  }
}

extern "C" void kernel_launch(void* const* d_in, const int* in_sizes, int n_in,
                              void* d_out, int out_size, void* d_ws,
                              size_t ws_size, hipStream_t stream) {
  const float* x = (const float*)d_in[0];
  const float* rms1w = (const float*)d_in[1];
  const float* ipw = (const float*)d_in[2];
  const float* cw = (const float*)d_in[3];
  const float* cb = (const float*)d_in[4];
  const float* xpw = (const float*)d_in[5];
  const float* dtw = (const float*)d_in[6];
  const float* dtb = (const float*)d_in[7];
  const float* A_log = (const float*)d_in[8];
  const float* Dskip = (const float*)d_in[9];
  const float* opw = (const float*)d_in[10];
  const float* rms2w = (const float*)d_in[11];
  const float* f1w = (const float*)d_in[12];
  const float* f1b = (const float*)d_in[13];
  const float* f2w = (const float*)d_in[14];
  const float* f2b = (const float*)d_in[15];
  const float* f3w = (const float*)d_in[16];
  const float* f3b = (const float*)d_in[17];
  float* out = (float*)d_out;

  float* rec = (float*)d_ws;                  // 50.3 MiB
  float* Pb = rec + (size_t)NCHT * CHF;       // 8 MiB
  float* Hb = Pb + SUMN;                      // 8 MiB
  float* segP = Hb + SUMN;                    // 256 KiB
  float* segH = segP + NBAT * NSEG * 512;     // 256 KiB
  float* carry = segH + NBAT * NSEG * 512;    // 256 KiB

  hipLaunchKernelGGL(k_prep, dim3(NROWS / 256), dim3(256), 0, stream, x, rms1w,
                     ipw, cw, cb, xpw, dtw, dtb, A_log, rec, Pb, Hb);
  hipLaunchKernelGGL(k_seg, dim3(256), dim3(256), 0, stream, Pb, Hb, segP,
                     segH);
  hipLaunchKernelGGL(k_carry, dim3(32), dim3(256), 0, stream, segP, segH,
                     carry);
  hipLaunchKernelGGL(k_scanmlp, dim3(NCHT), dim3(128), 0, stream, rec, x,
                     A_log, Hb, Pb, carry, rms1w, ipw, Dskip, opw, rms2w, f1w,
                     f1b, f2w, f2b, f3w, f3b, out);
}